// Round 1
// baseline (1002.125 us; speedup 1.0000x reference)
//
#include <hip/hip_runtime.h>
#include <hip/hip_bf16.h>

typedef __bf16 bf16_t;
typedef __bf16 v8bf __attribute__((ext_vector_type(8)));
typedef float  v4f  __attribute__((ext_vector_type(4)));

#define NSC   128   // scalar channels
#define NVC   64    // vector channels
#define DDIM  320   // NSC + 3*NVC
#define HIDN  128
#define K1DIM 320   // 2*NSC + NVC

__device__ __forceinline__ float siluf(float x) { return x / (1.f + __expf(-x)); }

// ---------------- weight transpose + bf16 conversion ----------------
__global__ void k_wconv(const float* __restrict__ esw1, const float* __restrict__ esw2,
                        const float* __restrict__ erw1, const float* __restrict__ erw2,
                        bf16_t* __restrict__ t1, bf16_t* __restrict__ t2,
                        bf16_t* __restrict__ t3, bf16_t* __restrict__ t4)
{
    const int gid = blockIdx.x * blockDim.x + threadIdx.x;
    const int stride = gridDim.x * blockDim.x;
    // t1: [128][320]  t1[n][k] = es_w1[k][n]
    for (int i = gid; i < 128*320; i += stride) { int n = i / 320, k = i % 320; t1[i] = (bf16_t)esw1[k*128 + n]; }
    // t2: [384][128]  t2[n][k] = es_w2[k][n]
    for (int i = gid; i < 384*128; i += stride) { int n = i / 128, k = i % 128; t2[i] = (bf16_t)esw2[k*384 + n]; }
    // t3: [128][32]   t3[n][k] = er_w1[k][n], zero-padded K 20->32
    for (int i = gid; i < 128*32;  i += stride) { int n = i / 32,  k = i % 32;  t3[i] = (k < 20) ? (bf16_t)erw1[k*128 + n] : (bf16_t)(0.f); }
    // t4: [384][128]  t4[n][k] = er_w2[k][n]
    for (int i = gid; i < 384*128; i += stride) { int n = i / 128, k = i % 128; t4[i] = (bf16_t)erw2[k*384 + n]; }
}

// ---------------- node prep: pre = o3_linear(nf, lin0); x = o3_linear(normgate(nf), lin1) ----------------
__global__ __launch_bounds__(256) void k_nodeprep(
    const float* __restrict__ nf,
    const float* __restrict__ w0s, const float* __restrict__ b0s, const float* __restrict__ w0v,
    const float* __restrict__ w1s, const float* __restrict__ b1s, const float* __restrict__ w1v,
    bf16_t* __restrict__ ps_bf, bf16_t* __restrict__ pv_bf,
    bf16_t* __restrict__ xs_bf, bf16_t* __restrict__ xv_bf, int N)
{
    __shared__ float s_in[16][128];
    __shared__ float vt[3][64][16];   // [m][c][node]
    const int tid = threadIdx.x;
    const int nb = blockIdx.x * 16;

    for (int idx = tid; idx < 16*320; idx += 256) {
        int n = idx / 320, c = idx % 320;
        int gn = nb + n; if (gn >= N) gn = N - 1;
        float v = nf[(size_t)gn*320 + c];
        if (c < 128) s_in[n][c] = v;
        else { int q = c - 128; vt[q % 3][q / 3][n] = v; }
    }
    __syncthreads();

    // ---- pass A: pre (lin0) ----
    {
        const int col = tid & 127, g = tid >> 7;
        float acc[8];
        #pragma unroll
        for (int j = 0; j < 8; ++j) acc[j] = 0.f;
        for (int c4 = 0; c4 < 128; c4 += 4) {
            float wa = w0s[(c4+0)*128 + col];
            float wb = w0s[(c4+1)*128 + col];
            float wc = w0s[(c4+2)*128 + col];
            float wd = w0s[(c4+3)*128 + col];
            #pragma unroll
            for (int j = 0; j < 8; ++j) {
                float4 sv = *(const float4*)&s_in[g*8+j][c4];
                acc[j] += sv.x*wa + sv.y*wb + sv.z*wc + sv.w*wd;
            }
        }
        float b = b0s[col];
        #pragma unroll
        for (int j = 0; j < 8; ++j) {
            int gn = nb + g*8 + j;
            if (gn < N) ps_bf[(size_t)gn*128 + col] = (bf16_t)(acc[j] + b);
        }
    }
    if (tid < 192) {
        const int d = tid & 63, m = tid >> 6;
        float acc[16];
        #pragma unroll
        for (int j = 0; j < 16; ++j) acc[j] = 0.f;
        for (int c = 0; c < 64; ++c) {
            float w = w0v[c*64 + d];
            float4 a0 = *(const float4*)&vt[m][c][0];
            float4 a1 = *(const float4*)&vt[m][c][4];
            float4 a2 = *(const float4*)&vt[m][c][8];
            float4 a3 = *(const float4*)&vt[m][c][12];
            acc[0]+=a0.x*w; acc[1]+=a0.y*w; acc[2]+=a0.z*w; acc[3]+=a0.w*w;
            acc[4]+=a1.x*w; acc[5]+=a1.y*w; acc[6]+=a1.z*w; acc[7]+=a1.w*w;
            acc[8]+=a2.x*w; acc[9]+=a2.y*w; acc[10]+=a2.z*w; acc[11]+=a2.w*w;
            acc[12]+=a3.x*w; acc[13]+=a3.y*w; acc[14]+=a3.z*w; acc[15]+=a3.w*w;
        }
        #pragma unroll
        for (int j = 0; j < 16; ++j) {
            int gn = nb + j;
            if (gn < N) pv_bf[(size_t)gn*192 + d*3 + m] = (bf16_t)acc[j];
        }
    }
    __syncthreads();

    // ---- normgate in place ----
    for (int idx = tid; idx < 2048; idx += 256) {
        int n = idx >> 7, c = idx & 127;
        s_in[n][c] = siluf(s_in[n][c]);
    }
    for (int idx = tid; idx < 1024; idx += 256) {
        int n = idx & 15, cc = idx >> 4;
        float v0 = vt[0][cc][n], v1 = vt[1][cc][n], v2 = vt[2][cc][n];
        float nn = sqrtf(v0*v0 + v1*v1 + v2*v2 + 1e-10f);
        float sc = 1.f / (1.f + __expf(-nn));     // silu(n)/n = sigmoid(n)
        vt[0][cc][n] = v0*sc; vt[1][cc][n] = v1*sc; vt[2][cc][n] = v2*sc;
    }
    __syncthreads();

    // ---- pass B: x (lin1) ----
    {
        const int col = tid & 127, g = tid >> 7;
        float acc[8];
        #pragma unroll
        for (int j = 0; j < 8; ++j) acc[j] = 0.f;
        for (int c4 = 0; c4 < 128; c4 += 4) {
            float wa = w1s[(c4+0)*128 + col];
            float wb = w1s[(c4+1)*128 + col];
            float wc = w1s[(c4+2)*128 + col];
            float wd = w1s[(c4+3)*128 + col];
            #pragma unroll
            for (int j = 0; j < 8; ++j) {
                float4 sv = *(const float4*)&s_in[g*8+j][c4];
                acc[j] += sv.x*wa + sv.y*wb + sv.z*wc + sv.w*wd;
            }
        }
        float b = b1s[col];
        #pragma unroll
        for (int j = 0; j < 8; ++j) {
            int gn = nb + g*8 + j;
            if (gn < N) xs_bf[(size_t)gn*128 + col] = (bf16_t)(acc[j] + b);
        }
    }
    if (tid < 192) {
        const int d = tid & 63, m = tid >> 6;
        float acc[16];
        #pragma unroll
        for (int j = 0; j < 16; ++j) acc[j] = 0.f;
        for (int c = 0; c < 64; ++c) {
            float w = w1v[c*64 + d];
            float4 a0 = *(const float4*)&vt[m][c][0];
            float4 a1 = *(const float4*)&vt[m][c][4];
            float4 a2 = *(const float4*)&vt[m][c][8];
            float4 a3 = *(const float4*)&vt[m][c][12];
            acc[0]+=a0.x*w; acc[1]+=a0.y*w; acc[2]+=a0.z*w; acc[3]+=a0.w*w;
            acc[4]+=a1.x*w; acc[5]+=a1.y*w; acc[6]+=a1.z*w; acc[7]+=a1.w*w;
            acc[8]+=a2.x*w; acc[9]+=a2.y*w; acc[10]+=a2.z*w; acc[11]+=a2.w*w;
            acc[12]+=a3.x*w; acc[13]+=a3.y*w; acc[14]+=a3.z*w; acc[15]+=a3.w*w;
        }
        #pragma unroll
        for (int j = 0; j < 16; ++j) {
            int gn = nb + j;
            if (gn < N) xv_bf[(size_t)gn*192 + d*3 + m] = (bf16_t)acc[j];
        }
    }
}

// ---------------- fused edge kernel: MLPs (MFMA bf16) + messages + atomic scatter ----------------
__global__ __launch_bounds__(512) void k_edge(
    const int* __restrict__ eidx, const float* __restrict__ rshs,
    const float* __restrict__ ea_g,
    const bf16_t* __restrict__ ps_bf, const bf16_t* __restrict__ pv_bf,
    const bf16_t* __restrict__ xs_bf, const bf16_t* __restrict__ xv_bf,
    const bf16_t* __restrict__ esw1t, const bf16_t* __restrict__ esw2t,
    const bf16_t* __restrict__ erw1t, const bf16_t* __restrict__ erw2t,
    const float* __restrict__ es_b1, const float* __restrict__ es_b2,
    const float* __restrict__ er_b1, const float* __restrict__ er_b2,
    float* __restrict__ accS, float* __restrict__ accV,
    int E)
{
    __shared__ bf16_t s0h[64*328];            // s0 tile (stride 328); reused for h1/h2 (stride 136)
    __shared__ bf16_t eat[64*40];             // edge_attr tile, K padded to 32
    __shared__ int   recv_l[64], send_l[64];
    __shared__ float y0_l[64];
    __shared__ float y1_l[64][3];

    const int tid  = threadIdx.x;
    const int lane = tid & 63;
    const int wid  = tid >> 6;
    const int e0   = blockIdx.x * 64;

    if (tid < 64) {
        int e = e0 + tid; if (e >= E) e = E - 1;
        recv_l[tid] = eidx[e];
        send_l[tid] = eidx[E + e];
        y0_l[tid]    = rshs[(size_t)e*4 + 0];
        y1_l[tid][0] = rshs[(size_t)e*4 + 1];
        y1_l[tid][1] = rshs[(size_t)e*4 + 2];
        y1_l[tid][2] = rshs[(size_t)e*4 + 3];
    }
    __syncthreads();

    // ---- stage s0 = [ps[recv] | ps[send] | vdot] and edge_attr tile ----
    #pragma unroll
    for (int rr = 0; rr < 8; ++rr) {
        int r = wid*8 + rr;
        int nr = recv_l[r], nsd = send_l[r];
        if (lane < 32) {
            *(uint2*)&s0h[r*328 + lane*4] = *(const uint2*)(ps_bf + (size_t)nr*NSC + lane*4);
        } else {
            int l2 = lane - 32;
            *(uint2*)&s0h[r*328 + 128 + l2*4] = *(const uint2*)(ps_bf + (size_t)nsd*NSC + l2*4);
        }
        const bf16_t* pr = pv_bf + (size_t)nr*192 + lane*3;
        const bf16_t* pn = pv_bf + (size_t)nsd*192 + lane*3;
        float d = (float)pr[0]*(float)pn[0] + (float)pr[1]*(float)pn[1] + (float)pr[2]*(float)pn[2];
        s0h[r*328 + 256 + lane] = (bf16_t)d;
        if (lane < 32) {
            int e = e0 + r;
            float v = (lane < 20 && e < E) ? ea_g[(size_t)e*20 + lane] : 0.f;
            eat[r*40 + lane] = (bf16_t)v;
        }
    }
    __syncthreads();

    const int mi = wid >> 1;       // M tile (16 edges)
    const int nj = wid & 1;        // N half
    const int lr = lane & 15;
    const int kg = lane >> 4;

    // ---- GEMM1: s0 @ es_w1 (K=320), GEMM3: ea @ er_w1 (K=32) ----
    v4f acc1[4], acc3[4];
    #pragma unroll
    for (int t = 0; t < 4; ++t) { acc1[t] = (v4f){0.f,0.f,0.f,0.f}; acc3[t] = (v4f){0.f,0.f,0.f,0.f}; }

    const bf16_t* aBase = &s0h[(mi*16 + lr)*328 + kg*8];
    #pragma unroll
    for (int kk = 0; kk < 10; ++kk) {
        v8bf a = *(const v8bf*)(aBase + kk*32);
        #pragma unroll
        for (int t = 0; t < 4; ++t) {
            v8bf b = *(const v8bf*)(esw1t + (size_t)(nj*64 + t*16 + lr)*K1DIM + kk*32 + kg*8);
            acc1[t] = __builtin_amdgcn_mfma_f32_16x16x32_bf16(a, b, acc1[t], 0, 0, 0);
        }
    }
    {
        v8bf a = *(const v8bf*)&eat[(mi*16 + lr)*40 + kg*8];
        #pragma unroll
        for (int t = 0; t < 4; ++t) {
            v8bf b = *(const v8bf*)(erw1t + (size_t)(nj*64 + t*16 + lr)*32 + kg*8);
            acc3[t] = __builtin_amdgcn_mfma_f32_16x16x32_bf16(a, b, acc3[t], 0, 0, 0);
        }
    }
    __syncthreads();   // all reads of s0h/eat done; reuse s0h for h1/h2

    bf16_t* h1 = s0h;              // 64 x 128, stride 136
    bf16_t* h2 = s0h + 64*136;
    #pragma unroll
    for (int t = 0; t < 4; ++t) {
        int col = nj*64 + t*16 + lr;
        float be = es_b1[col];
        float br = er_b1[col];
        #pragma unroll
        for (int r = 0; r < 4; ++r) {
            int row = mi*16 + kg*4 + r;
            h1[row*136 + col] = (bf16_t)siluf(acc1[t][r] + be);
            h2[row*136 + col] = (bf16_t)siluf(acc3[t][r] + br);
        }
    }
    __syncthreads();

    // ---- GEMM2/GEMM4 in 3 column chunks of 128, fused messages + atomics ----
    #pragma unroll
    for (int ch = 0; ch < 3; ++ch) {
        v4f aes[4], aer[4];
        #pragma unroll
        for (int t = 0; t < 4; ++t) { aes[t] = (v4f){0.f,0.f,0.f,0.f}; aer[t] = (v4f){0.f,0.f,0.f,0.f}; }
        #pragma unroll
        for (int kk = 0; kk < 4; ++kk) {
            v8bf a1 = *(const v8bf*)&h1[(mi*16 + lr)*136 + kk*32 + kg*8];
            v8bf a2 = *(const v8bf*)&h2[(mi*16 + lr)*136 + kk*32 + kg*8];
            #pragma unroll
            for (int t = 0; t < 4; ++t) {
                size_t nrow = (size_t)(ch*128 + nj*64 + t*16 + lr)*HIDN + kk*32 + kg*8;
                v8bf b1 = *(const v8bf*)(esw2t + nrow);
                v8bf b2 = *(const v8bf*)(erw2t + nrow);
                aes[t] = __builtin_amdgcn_mfma_f32_16x16x32_bf16(a1, b1, aes[t], 0, 0, 0);
                aer[t] = __builtin_amdgcn_mfma_f32_16x16x32_bf16(a2, b2, aer[t], 0, 0, 0);
            }
        }
        #pragma unroll
        for (int t = 0; t < 4; ++t) {
            int col = ch*128 + nj*64 + t*16 + lr;
            float be = es_b2[col], br = er_b2[col];
            #pragma unroll
            for (int r = 0; r < 4; ++r) {
                int row = mi*16 + kg*4 + r;
                int e = e0 + row;
                if (e >= E) continue;
                float w = (aes[t][r] + be) * (aer[t][r] + br);
                int nr  = recv_l[row], nsd = send_l[row];
                float y0 = y0_l[row];
                if (ch == 0) {
                    // w1: m_s1 = xs_j * y0 * w1  -> acc_s[:, col]
                    float xs = (float)xs_bf[(size_t)nsd*NSC + col];
                    atomicAdd(accS + (size_t)nr*192 + col, xs * y0 * w);
                } else if (ch == 1) {
                    // w2: m_v1 = xs_j * y1[m] * w2 -> acc_v[:, c, m]
                    int c = col - 128;
                    float xs = (float)xs_bf[(size_t)nsd*NSC + c];
                    float a = xs * w;
                    float* bp = accV + (size_t)nr*576 + c*3;
                    atomicAdd(bp + 0, a * y1_l[row][0]);
                    atomicAdd(bp + 1, a * y1_l[row][1]);
                    atomicAdd(bp + 2, a * y1_l[row][2]);
                } else if (nj == 0) {
                    // w3: m_v2 = xv_j * (y0*w3) -> acc_v[:, 128+cc, m]
                    int cc = col - 256;
                    const bf16_t* xv = xv_bf + (size_t)nsd*192 + cc*3;
                    float s = y0 * w;
                    float* bp = accV + (size_t)nr*576 + (128 + cc)*3;
                    atomicAdd(bp + 0, (float)xv[0] * s);
                    atomicAdd(bp + 1, (float)xv[1] * s);
                    atomicAdd(bp + 2, (float)xv[2] * s);
                } else {
                    // w4: m_s2 = dot(xv_j, y1) * w4 / sqrt(3) -> acc_s[:, 128+cc]
                    int cc = col - 320;
                    const bf16_t* xv = xv_bf + (size_t)nsd*192 + cc*3;
                    float s2 = (float)xv[0]*y1_l[row][0] + (float)xv[1]*y1_l[row][1] + (float)xv[2]*y1_l[row][2];
                    atomicAdd(accS + (size_t)nr*192 + 128 + cc, s2 * w * 0.57735026918962576f);
                }
            }
        }
    }
}

// ---------------- node out: lin2 + layernorm + vector norm + residual ----------------
__global__ __launch_bounds__(256) void k_nodeout(
    const float* __restrict__ accS, const float* __restrict__ accV,
    const float* __restrict__ nf,
    const float* __restrict__ w2s, const float* __restrict__ b2s, const float* __restrict__ w2v,
    const float* __restrict__ ln_gs, const float* __restrict__ ln_bs, const float* __restrict__ ln_gv,
    float* __restrict__ out, int N)
{
    __shared__ float as_l[16][192];
    __shared__ float avt[3][192][16];   // [m][c][node]
    __shared__ float os_l[16][128];
    __shared__ float ov_l[16][192];
    const int tid = threadIdx.x;
    const int nb = blockIdx.x * 16;

    for (int idx = tid; idx < 16*192; idx += 256) {
        int n = idx / 192, c = idx % 192;
        int gn = nb + n; if (gn >= N) gn = N - 1;
        as_l[n][c] = accS[(size_t)gn*192 + c];
    }
    for (int idx = tid; idx < 16*576; idx += 256) {
        int n = idx / 576, q = idx % 576;
        int gn = nb + n; if (gn >= N) gn = N - 1;
        avt[q % 3][q / 3][n] = accV[(size_t)gn*576 + q];
    }
    __syncthreads();

    {
        const int col = tid & 127, g = tid >> 7;
        float acc[8];
        #pragma unroll
        for (int j = 0; j < 8; ++j) acc[j] = 0.f;
        for (int c4 = 0; c4 < 192; c4 += 4) {
            float wa = w2s[(c4+0)*128 + col];
            float wb = w2s[(c4+1)*128 + col];
            float wc = w2s[(c4+2)*128 + col];
            float wd = w2s[(c4+3)*128 + col];
            #pragma unroll
            for (int j = 0; j < 8; ++j) {
                float4 sv = *(const float4*)&as_l[g*8+j][c4];
                acc[j] += sv.x*wa + sv.y*wb + sv.z*wc + sv.w*wd;
            }
        }
        float b = b2s[col];
        #pragma unroll
        for (int j = 0; j < 8; ++j) os_l[g*8+j][col] = acc[j] + b;
    }
    if (tid < 192) {
        const int d = tid & 63, m = tid >> 6;
        float acc[16];
        #pragma unroll
        for (int j = 0; j < 16; ++j) acc[j] = 0.f;
        for (int c = 0; c < 192; ++c) {
            float w = w2v[c*64 + d];
            float4 a0 = *(const float4*)&avt[m][c][0];
            float4 a1 = *(const float4*)&avt[m][c][4];
            float4 a2 = *(const float4*)&avt[m][c][8];
            float4 a3 = *(const float4*)&avt[m][c][12];
            acc[0]+=a0.x*w; acc[1]+=a0.y*w; acc[2]+=a0.z*w; acc[3]+=a0.w*w;
            acc[4]+=a1.x*w; acc[5]+=a1.y*w; acc[6]+=a1.z*w; acc[7]+=a1.w*w;
            acc[8]+=a2.x*w; acc[9]+=a2.y*w; acc[10]+=a2.z*w; acc[11]+=a2.w*w;
            acc[12]+=a3.x*w; acc[13]+=a3.y*w; acc[14]+=a3.z*w; acc[15]+=a3.w*w;
        }
        #pragma unroll
        for (int j = 0; j < 16; ++j) ov_l[j][d*3 + m] = acc[j];
    }
    __syncthreads();

    const int lane = tid & 63, wid = tid >> 6;
    for (int i = 0; i < 4; ++i) {
        int n = wid*4 + i;
        int gn = nb + n;
        float x0 = os_l[n][lane], x1 = os_l[n][lane + 64];
        float s = x0 + x1;
        #pragma unroll
        for (int off = 32; off > 0; off >>= 1) s += __shfl_xor(s, off);
        float mu = s * (1.f/128.f);
        float d0 = x0 - mu, d1 = x1 - mu;
        float q = d0*d0 + d1*d1;
        #pragma unroll
        for (int off = 32; off > 0; off >>= 1) q += __shfl_xor(q, off);
        float var = q * (1.f/128.f);
        float v0 = ov_l[n][lane], v1 = ov_l[n][lane + 64], v2 = ov_l[n][lane + 128];
        float q2 = v0*v0 + v1*v1 + v2*v2;
        #pragma unroll
        for (int off = 32; off > 0; off >>= 1) q2 += __shfl_xor(q2, off);
        float n2 = q2 * (1.f/64.f);
        float rstd = rsqrtf(var + 1e-5f);
        float rn2  = rsqrtf(n2 + 1e-5f);
        if (gn < N) {
            size_t base = (size_t)gn * 320;
            float o0 = (x0 - mu)*rstd*ln_gs[lane] + ln_bs[lane];
            out[base + lane] = nf[base + lane] + o0;
            float o1 = (x1 - mu)*rstd*ln_gs[lane + 64] + ln_bs[lane + 64];
            out[base + 64 + lane] = nf[base + 64 + lane] + o1;
            #pragma unroll
            for (int k3 = 0; k3 < 3; ++k3) {
                int idx = lane + k3*64;        // 0..191, = d*3+m
                float vv = ov_l[n][idx];
                int d = idx / 3;
                out[base + 128 + idx] = nf[base + 128 + idx] + vv * rn2 * ln_gv[128 + d];
            }
        }
    }
}

extern "C" void kernel_launch(void* const* d_in, const int* in_sizes, int n_in,
                              void* d_out, int out_size, void* d_ws, size_t ws_size,
                              hipStream_t stream)
{
    const float* nf    = (const float*)d_in[0];
    const float* ea_g  = (const float*)d_in[1];
    const float* rshs  = (const float*)d_in[2];
    const int*   eidx  = (const int*)  d_in[3];
    const float* w0s   = (const float*)d_in[4];
    const float* b0s   = (const float*)d_in[5];
    const float* w0v   = (const float*)d_in[6];
    const float* w1s   = (const float*)d_in[7];
    const float* b1s   = (const float*)d_in[8];
    const float* w1v   = (const float*)d_in[9];
    const float* w2s   = (const float*)d_in[10];
    const float* b2s   = (const float*)d_in[11];
    const float* w2v   = (const float*)d_in[12];
    const float* esw1  = (const float*)d_in[13];
    const float* esb1  = (const float*)d_in[14];
    const float* esw2  = (const float*)d_in[15];
    const float* esb2  = (const float*)d_in[16];
    const float* erw1  = (const float*)d_in[17];
    const float* erb1  = (const float*)d_in[18];
    const float* erw2  = (const float*)d_in[19];
    const float* erb2  = (const float*)d_in[20];
    const float* ln_gs = (const float*)d_in[21];
    const float* ln_bs = (const float*)d_in[22];
    const float* ln_gv = (const float*)d_in[23];

    const int N = in_sizes[0] / DDIM;
    const int E = in_sizes[3] / 2;

    // workspace layout
    float* accS = (float*)d_ws;                                // N*192 f32
    float* accV = accS + (size_t)N*192;                        // N*576 f32
    bf16_t* ps_bf = (bf16_t*)(accV + (size_t)N*576);           // N*128
    bf16_t* pv_bf = ps_bf + (size_t)N*128;                     // N*192
    bf16_t* xs_bf = pv_bf + (size_t)N*192;                     // N*128
    bf16_t* xv_bf = xs_bf + (size_t)N*128;                     // N*192
    bf16_t* esw1t = xv_bf + (size_t)N*192;                     // 128*320
    bf16_t* esw2t = esw1t + 128*320;                           // 384*128
    bf16_t* erw1t = esw2t + 384*128;                           // 128*32
    bf16_t* erw2t = erw1t + 128*32;                            // 384*128

    hipMemsetAsync(accS, 0, (size_t)N*768*sizeof(float), stream);
    k_wconv<<<64, 256, 0, stream>>>(esw1, esw2, erw1, erw2, esw1t, esw2t, erw1t, erw2t);
    k_nodeprep<<<(N + 15)/16, 256, 0, stream>>>(nf, w0s, b0s, w0v, w1s, b1s, w1v,
                                                ps_bf, pv_bf, xs_bf, xv_bf, N);
    k_edge<<<(E + 63)/64, 512, 0, stream>>>(eidx, rshs, ea_g, ps_bf, pv_bf, xs_bf, xv_bf,
                                            esw1t, esw2t, erw1t, erw2t,
                                            esb1, esb2, erb1, erb2, accS, accV, E);
    k_nodeout<<<(N + 15)/16, 256, 0, stream>>>(accS, accV, nf, w2s, b2s, w2v,
                                               ln_gs, ln_bs, ln_gv, (float*)d_out, N);
}

// Round 2
// 533.401 us; speedup vs baseline: 1.8787x; 1.8787x over previous
//
#include <hip/hip_runtime.h>
#include <hip/hip_bf16.h>

typedef __bf16 bf16_t;
typedef __bf16 v8bf __attribute__((ext_vector_type(8)));
typedef float  v4f  __attribute__((ext_vector_type(4)));

#define NSC   128   // scalar channels
#define NVC   64    // vector channels
#define DDIM  320   // NSC + 3*NVC
#define HIDN  128
#define K1DIM 320   // 2*NSC + NVC
#define WNUM  384

__device__ __forceinline__ float siluf(float x) { return x / (1.f + __expf(-x)); }

// ---------------- weight transpose + bf16 conversion ----------------
__global__ void k_wconv(const float* __restrict__ esw1, const float* __restrict__ esw2,
                        const float* __restrict__ erw1, const float* __restrict__ erw2,
                        bf16_t* __restrict__ t1, bf16_t* __restrict__ t2,
                        bf16_t* __restrict__ t3, bf16_t* __restrict__ t4)
{
    const int gid = blockIdx.x * blockDim.x + threadIdx.x;
    const int stride = gridDim.x * blockDim.x;
    for (int i = gid; i < 128*320; i += stride) { int n = i / 320, k = i % 320; t1[i] = (bf16_t)esw1[k*128 + n]; }
    for (int i = gid; i < 384*128; i += stride) { int n = i / 128, k = i % 128; t2[i] = (bf16_t)esw2[k*384 + n]; }
    for (int i = gid; i < 128*32;  i += stride) { int n = i / 32,  k = i % 32;  t3[i] = (k < 20) ? (bf16_t)erw1[k*128 + n] : (bf16_t)(0.f); }
    for (int i = gid; i < 384*128; i += stride) { int n = i / 128, k = i % 128; t4[i] = (bf16_t)erw2[k*384 + n]; }
}

// ---------------- counting sort by recv ----------------
__global__ void k_hist(const int* __restrict__ eidx, int* __restrict__ hist, int E)
{
    for (int e = blockIdx.x * blockDim.x + threadIdx.x; e < E; e += gridDim.x * blockDim.x)
        atomicAdd(&hist[eidx[e]], 1);
}

__global__ __launch_bounds__(1024) void k_scan(const int* __restrict__ hist,
                                               int* __restrict__ off, int* __restrict__ cnt, int N)
{
    __shared__ int part[1024];
    const int tid = threadIdx.x;
    const int C = (N + 1023) >> 10;
    const int base = tid * C;
    int s = 0;
    for (int j = 0; j < C; ++j) { int idx = base + j; if (idx < N) s += hist[idx]; }
    part[tid] = s;
    __syncthreads();
    for (int d = 1; d < 1024; d <<= 1) {
        int u = (tid >= d) ? part[tid - d] : 0;
        __syncthreads();
        part[tid] += u;
        __syncthreads();
    }
    int run = part[tid] - s;   // exclusive prefix of this thread's chunk
    for (int j = 0; j < C; ++j) {
        int idx = base + j;
        if (idx < N) { off[idx] = run; cnt[idx] = run; run += hist[idx]; }
    }
    if (tid == 1023) off[N] = part[1023];
}

__global__ void k_scatter(const int* __restrict__ eidx, int* __restrict__ cnt,
                          int* __restrict__ perm, int E)
{
    for (int e = blockIdx.x * blockDim.x + threadIdx.x; e < E; e += gridDim.x * blockDim.x) {
        int pos = atomicAdd(&cnt[eidx[e]], 1);
        perm[pos] = e;
    }
}

// ---------------- node prep: pre = o3_linear(nf, lin0); x = o3_linear(normgate(nf), lin1) ----------------
__global__ __launch_bounds__(256) void k_nodeprep(
    const float* __restrict__ nf,
    const float* __restrict__ w0s, const float* __restrict__ b0s, const float* __restrict__ w0v,
    const float* __restrict__ w1s, const float* __restrict__ b1s, const float* __restrict__ w1v,
    bf16_t* __restrict__ ps_bf, bf16_t* __restrict__ pv_bf,
    bf16_t* __restrict__ xs_bf, bf16_t* __restrict__ xv_bf, int N)
{
    __shared__ float s_in[16][128];
    __shared__ float vt[3][64][16];   // [m][c][node]
    const int tid = threadIdx.x;
    const int nb = blockIdx.x * 16;

    for (int idx = tid; idx < 16*320; idx += 256) {
        int n = idx / 320, c = idx % 320;
        int gn = nb + n; if (gn >= N) gn = N - 1;
        float v = nf[(size_t)gn*320 + c];
        if (c < 128) s_in[n][c] = v;
        else { int q = c - 128; vt[q % 3][q / 3][n] = v; }
    }
    __syncthreads();

    {
        const int col = tid & 127, g = tid >> 7;
        float acc[8];
        #pragma unroll
        for (int j = 0; j < 8; ++j) acc[j] = 0.f;
        for (int c4 = 0; c4 < 128; c4 += 4) {
            float wa = w0s[(c4+0)*128 + col];
            float wb = w0s[(c4+1)*128 + col];
            float wc = w0s[(c4+2)*128 + col];
            float wd = w0s[(c4+3)*128 + col];
            #pragma unroll
            for (int j = 0; j < 8; ++j) {
                float4 sv = *(const float4*)&s_in[g*8+j][c4];
                acc[j] += sv.x*wa + sv.y*wb + sv.z*wc + sv.w*wd;
            }
        }
        float b = b0s[col];
        #pragma unroll
        for (int j = 0; j < 8; ++j) {
            int gn = nb + g*8 + j;
            if (gn < N) ps_bf[(size_t)gn*128 + col] = (bf16_t)(acc[j] + b);
        }
    }
    if (tid < 192) {
        const int d = tid & 63, m = tid >> 6;
        float acc[16];
        #pragma unroll
        for (int j = 0; j < 16; ++j) acc[j] = 0.f;
        for (int c = 0; c < 64; ++c) {
            float w = w0v[c*64 + d];
            float4 a0 = *(const float4*)&vt[m][c][0];
            float4 a1 = *(const float4*)&vt[m][c][4];
            float4 a2 = *(const float4*)&vt[m][c][8];
            float4 a3 = *(const float4*)&vt[m][c][12];
            acc[0]+=a0.x*w; acc[1]+=a0.y*w; acc[2]+=a0.z*w; acc[3]+=a0.w*w;
            acc[4]+=a1.x*w; acc[5]+=a1.y*w; acc[6]+=a1.z*w; acc[7]+=a1.w*w;
            acc[8]+=a2.x*w; acc[9]+=a2.y*w; acc[10]+=a2.z*w; acc[11]+=a2.w*w;
            acc[12]+=a3.x*w; acc[13]+=a3.y*w; acc[14]+=a3.z*w; acc[15]+=a3.w*w;
        }
        #pragma unroll
        for (int j = 0; j < 16; ++j) {
            int gn = nb + j;
            if (gn < N) pv_bf[(size_t)gn*192 + d*3 + m] = (bf16_t)acc[j];
        }
    }
    __syncthreads();

    for (int idx = tid; idx < 2048; idx += 256) {
        int n = idx >> 7, c = idx & 127;
        s_in[n][c] = siluf(s_in[n][c]);
    }
    for (int idx = tid; idx < 1024; idx += 256) {
        int n = idx & 15, cc = idx >> 4;
        float v0 = vt[0][cc][n], v1 = vt[1][cc][n], v2 = vt[2][cc][n];
        float nn = sqrtf(v0*v0 + v1*v1 + v2*v2 + 1e-10f);
        float sc = 1.f / (1.f + __expf(-nn));
        vt[0][cc][n] = v0*sc; vt[1][cc][n] = v1*sc; vt[2][cc][n] = v2*sc;
    }
    __syncthreads();

    {
        const int col = tid & 127, g = tid >> 7;
        float acc[8];
        #pragma unroll
        for (int j = 0; j < 8; ++j) acc[j] = 0.f;
        for (int c4 = 0; c4 < 128; c4 += 4) {
            float wa = w1s[(c4+0)*128 + col];
            float wb = w1s[(c4+1)*128 + col];
            float wc = w1s[(c4+2)*128 + col];
            float wd = w1s[(c4+3)*128 + col];
            #pragma unroll
            for (int j = 0; j < 8; ++j) {
                float4 sv = *(const float4*)&s_in[g*8+j][c4];
                acc[j] += sv.x*wa + sv.y*wb + sv.z*wc + sv.w*wd;
            }
        }
        float b = b1s[col];
        #pragma unroll
        for (int j = 0; j < 8; ++j) {
            int gn = nb + g*8 + j;
            if (gn < N) xs_bf[(size_t)gn*128 + col] = (bf16_t)(acc[j] + b);
        }
    }
    if (tid < 192) {
        const int d = tid & 63, m = tid >> 6;
        float acc[16];
        #pragma unroll
        for (int j = 0; j < 16; ++j) acc[j] = 0.f;
        for (int c = 0; c < 64; ++c) {
            float w = w1v[c*64 + d];
            float4 a0 = *(const float4*)&vt[m][c][0];
            float4 a1 = *(const float4*)&vt[m][c][4];
            float4 a2 = *(const float4*)&vt[m][c][8];
            float4 a3 = *(const float4*)&vt[m][c][12];
            acc[0]+=a0.x*w; acc[1]+=a0.y*w; acc[2]+=a0.z*w; acc[3]+=a0.w*w;
            acc[4]+=a1.x*w; acc[5]+=a1.y*w; acc[6]+=a1.z*w; acc[7]+=a1.w*w;
            acc[8]+=a2.x*w; acc[9]+=a2.y*w; acc[10]+=a2.z*w; acc[11]+=a2.w*w;
            acc[12]+=a3.x*w; acc[13]+=a3.y*w; acc[14]+=a3.z*w; acc[15]+=a3.w*w;
        }
        #pragma unroll
        for (int j = 0; j < 16; ++j) {
            int gn = nb + j;
            if (gn < N) xv_bf[(size_t)gn*192 + d*3 + m] = (bf16_t)acc[j];
        }
    }
}

// ---------------- edge MLP (MFMA bf16) -> w[E][384] bf16, no atomics ----------------
__global__ __launch_bounds__(512) void k_edge2(
    const int* __restrict__ eidx, const float* __restrict__ ea_g,
    const bf16_t* __restrict__ ps_bf, const bf16_t* __restrict__ pv_bf,
    const bf16_t* __restrict__ esw1t, const bf16_t* __restrict__ esw2t,
    const bf16_t* __restrict__ erw1t, const bf16_t* __restrict__ erw2t,
    const float* __restrict__ es_b1, const float* __restrict__ es_b2,
    const float* __restrict__ er_b1, const float* __restrict__ er_b2,
    bf16_t* __restrict__ w_bf, int E)
{
    __shared__ bf16_t s0h[64*328];            // s0 tile (stride 328); reused for h1/h2 (stride 136)
    __shared__ bf16_t eat[64*40];             // edge_attr tile, K padded to 32
    __shared__ int   recv_l[64], send_l[64];

    const int tid  = threadIdx.x;
    const int lane = tid & 63;
    const int wid  = tid >> 6;
    const int e0   = blockIdx.x * 64;

    if (tid < 64) {
        int e = e0 + tid; if (e >= E) e = E - 1;
        recv_l[tid] = eidx[e];
        send_l[tid] = eidx[E + e];
    }
    __syncthreads();

    #pragma unroll
    for (int rr = 0; rr < 8; ++rr) {
        int r = wid*8 + rr;
        int nr = recv_l[r], nsd = send_l[r];
        if (lane < 32) {
            *(uint2*)&s0h[r*328 + lane*4] = *(const uint2*)(ps_bf + (size_t)nr*NSC + lane*4);
        } else {
            int l2 = lane - 32;
            *(uint2*)&s0h[r*328 + 128 + l2*4] = *(const uint2*)(ps_bf + (size_t)nsd*NSC + l2*4);
        }
        const bf16_t* pr = pv_bf + (size_t)nr*192 + lane*3;
        const bf16_t* pn = pv_bf + (size_t)nsd*192 + lane*3;
        float d = (float)pr[0]*(float)pn[0] + (float)pr[1]*(float)pn[1] + (float)pr[2]*(float)pn[2];
        s0h[r*328 + 256 + lane] = (bf16_t)d;
        if (lane < 32) {
            int e = e0 + r;
            float v = (lane < 20 && e < E) ? ea_g[(size_t)e*20 + lane] : 0.f;
            eat[r*40 + lane] = (bf16_t)v;
        }
    }
    __syncthreads();

    const int mi = wid >> 1;
    const int nj = wid & 1;
    const int lr = lane & 15;
    const int kg = lane >> 4;

    v4f acc1[4], acc3[4];
    #pragma unroll
    for (int t = 0; t < 4; ++t) { acc1[t] = (v4f){0.f,0.f,0.f,0.f}; acc3[t] = (v4f){0.f,0.f,0.f,0.f}; }

    const bf16_t* aBase = &s0h[(mi*16 + lr)*328 + kg*8];
    #pragma unroll
    for (int kk = 0; kk < 10; ++kk) {
        v8bf a = *(const v8bf*)(aBase + kk*32);
        #pragma unroll
        for (int t = 0; t < 4; ++t) {
            v8bf b = *(const v8bf*)(esw1t + (size_t)(nj*64 + t*16 + lr)*K1DIM + kk*32 + kg*8);
            acc1[t] = __builtin_amdgcn_mfma_f32_16x16x32_bf16(a, b, acc1[t], 0, 0, 0);
        }
    }
    {
        v8bf a = *(const v8bf*)&eat[(mi*16 + lr)*40 + kg*8];
        #pragma unroll
        for (int t = 0; t < 4; ++t) {
            v8bf b = *(const v8bf*)(erw1t + (size_t)(nj*64 + t*16 + lr)*32 + kg*8);
            acc3[t] = __builtin_amdgcn_mfma_f32_16x16x32_bf16(a, b, acc3[t], 0, 0, 0);
        }
    }
    __syncthreads();

    bf16_t* h1 = s0h;              // 64 x 128, stride 136
    bf16_t* h2 = s0h + 64*136;
    #pragma unroll
    for (int t = 0; t < 4; ++t) {
        int col = nj*64 + t*16 + lr;
        float be = es_b1[col];
        float br = er_b1[col];
        #pragma unroll
        for (int r = 0; r < 4; ++r) {
            int row = mi*16 + kg*4 + r;
            h1[row*136 + col] = (bf16_t)siluf(acc1[t][r] + be);
            h2[row*136 + col] = (bf16_t)siluf(acc3[t][r] + br);
        }
    }
    __syncthreads();

    #pragma unroll
    for (int ch = 0; ch < 3; ++ch) {
        v4f aes[4], aer[4];
        #pragma unroll
        for (int t = 0; t < 4; ++t) { aes[t] = (v4f){0.f,0.f,0.f,0.f}; aer[t] = (v4f){0.f,0.f,0.f,0.f}; }
        #pragma unroll
        for (int kk = 0; kk < 4; ++kk) {
            v8bf a1 = *(const v8bf*)&h1[(mi*16 + lr)*136 + kk*32 + kg*8];
            v8bf a2 = *(const v8bf*)&h2[(mi*16 + lr)*136 + kk*32 + kg*8];
            #pragma unroll
            for (int t = 0; t < 4; ++t) {
                size_t nrow = (size_t)(ch*128 + nj*64 + t*16 + lr)*HIDN + kk*32 + kg*8;
                v8bf b1 = *(const v8bf*)(esw2t + nrow);
                v8bf b2 = *(const v8bf*)(erw2t + nrow);
                aes[t] = __builtin_amdgcn_mfma_f32_16x16x32_bf16(a1, b1, aes[t], 0, 0, 0);
                aer[t] = __builtin_amdgcn_mfma_f32_16x16x32_bf16(a2, b2, aer[t], 0, 0, 0);
            }
        }
        #pragma unroll
        for (int t = 0; t < 4; ++t) {
            int col = ch*128 + nj*64 + t*16 + lr;
            float be = es_b2[col], br = er_b2[col];
            #pragma unroll
            for (int r = 0; r < 4; ++r) {
                int row = mi*16 + kg*4 + r;
                int e = e0 + row;
                if (e < E) w_bf[(size_t)e*WNUM + col] = (bf16_t)((aes[t][r] + be) * (aer[t][r] + br));
            }
        }
    }
}

// ---------------- per-node gather + lin2 + norms + residual (no atomics) ----------------
__global__ __launch_bounds__(256) void k_gather(
    const int* __restrict__ perm, const int* __restrict__ off,
    const int* __restrict__ eidx, const float* __restrict__ rshs,
    const bf16_t* __restrict__ xs_bf, const bf16_t* __restrict__ xv_bf,
    const bf16_t* __restrict__ w_bf,
    const float* __restrict__ nf,
    const float* __restrict__ w2s, const float* __restrict__ b2s, const float* __restrict__ w2v,
    const float* __restrict__ ln_gs, const float* __restrict__ ln_bs, const float* __restrict__ ln_gv,
    float* __restrict__ out, int N, int E)
{
    __shared__ float accS_l[192];
    __shared__ float accV_l[576];
    __shared__ float os_l[128];
    __shared__ float ov_l[192];
    __shared__ float stats[3];
    const int tid = threadIdx.x;
    const int n = blockIdx.x;
    const int i0 = off[n], i1 = off[n+1];

    float a0 = 0.f, a1 = 0.f, a2 = 0.f, a3 = 0.f;
    if (tid < 128) {
        const int c = tid;
        for (int i = i0; i < i1; ++i) {
            int e = perm[i];
            int nsd = eidx[E + e];
            float4 y = *(const float4*)(rshs + (size_t)e*4);
            float w1 = (float)w_bf[(size_t)e*WNUM + c];
            float w2 = (float)w_bf[(size_t)e*WNUM + 128 + c];
            float xs = (float)xs_bf[(size_t)nsd*NSC + c];
            a0 += xs * y.x * w1;
            float xw = xs * w2;
            a1 += xw * y.y; a2 += xw * y.z; a3 += xw * y.w;
        }
        accS_l[c] = a0;
        accV_l[c*3+0] = a1; accV_l[c*3+1] = a2; accV_l[c*3+2] = a3;
    } else if (tid < 192) {
        const int u = tid - 128;
        for (int i = i0; i < i1; ++i) {
            int e = perm[i];
            int nsd = eidx[E + e];
            float4 y = *(const float4*)(rshs + (size_t)e*4);
            float w3 = (float)w_bf[(size_t)e*WNUM + 256 + u];
            float w4 = (float)w_bf[(size_t)e*WNUM + 320 + u];
            const bf16_t* xv = xv_bf + (size_t)nsd*192 + u*3;
            float v0 = (float)xv[0], v1 = (float)xv[1], v2 = (float)xv[2];
            a0 += (v0*y.y + v1*y.z + v2*y.w) * w4 * 0.57735026918962576f;
            float s = y.x * w3;
            a1 += v0*s; a2 += v1*s; a3 += v2*s;
        }
        accS_l[128+u] = a0;
        accV_l[(128+u)*3+0] = a1; accV_l[(128+u)*3+1] = a2; accV_l[(128+u)*3+2] = a3;
    }
    __syncthreads();

    // lin2
    if (tid < 128) {
        float acc = 0.f;
        #pragma unroll 4
        for (int c = 0; c < 192; ++c) acc += accS_l[c] * w2s[c*128 + tid];
        os_l[tid] = acc + b2s[tid];
    } else {
        int q = tid - 128;
        for (int o = q; o < 192; o += 128) {
            int m = o % 3, d = o / 3;
            float acc = 0.f;
            #pragma unroll 4
            for (int c = 0; c < 192; ++c) acc += accV_l[c*3 + m] * w2v[c*64 + d];
            ov_l[o] = acc;
        }
    }
    __syncthreads();

    // norms (wave 0)
    if (tid < 64) {
        float x0 = os_l[tid], x1 = os_l[tid + 64];
        float s = x0 + x1;
        #pragma unroll
        for (int o = 32; o > 0; o >>= 1) s += __shfl_xor(s, o);
        float mu = s * (1.f/128.f);
        float d0 = x0 - mu, d1 = x1 - mu;
        float q = d0*d0 + d1*d1;
        #pragma unroll
        for (int o = 32; o > 0; o >>= 1) q += __shfl_xor(q, o);
        float var = q * (1.f/128.f);
        float v0 = ov_l[tid], v1 = ov_l[tid + 64], v2 = ov_l[tid + 128];
        float q2 = v0*v0 + v1*v1 + v2*v2;
        #pragma unroll
        for (int o = 32; o > 0; o >>= 1) q2 += __shfl_xor(q2, o);
        float n2 = q2 * (1.f/64.f);
        if (tid == 0) {
            stats[0] = mu;
            stats[1] = rsqrtf(var + 1e-5f);
            stats[2] = rsqrtf(n2 + 1e-5f);
        }
    }
    __syncthreads();

    const float mu = stats[0], rstd = stats[1], rn2 = stats[2];
    const size_t base = (size_t)n * DDIM;
    for (int i = tid; i < DDIM; i += 256) {
        if (i < 128) {
            out[base + i] = nf[base + i] + (os_l[i] - mu) * rstd * ln_gs[i] + ln_bs[i];
        } else {
            int o = i - 128;
            int d = o / 3;
            out[base + i] = nf[base + i] + ov_l[o] * rn2 * ln_gv[128 + d];
        }
    }
}

static inline size_t align64(size_t x) { return (x + 63) & ~(size_t)63; }

extern "C" void kernel_launch(void* const* d_in, const int* in_sizes, int n_in,
                              void* d_out, int out_size, void* d_ws, size_t ws_size,
                              hipStream_t stream)
{
    const float* nf    = (const float*)d_in[0];
    const float* ea_g  = (const float*)d_in[1];
    const float* rshs  = (const float*)d_in[2];
    const int*   eidx  = (const int*)  d_in[3];
    const float* w0s   = (const float*)d_in[4];
    const float* b0s   = (const float*)d_in[5];
    const float* w0v   = (const float*)d_in[6];
    const float* w1s   = (const float*)d_in[7];
    const float* b1s   = (const float*)d_in[8];
    const float* w1v   = (const float*)d_in[9];
    const float* w2s   = (const float*)d_in[10];
    const float* b2s   = (const float*)d_in[11];
    const float* w2v   = (const float*)d_in[12];
    const float* esw1  = (const float*)d_in[13];
    const float* esb1  = (const float*)d_in[14];
    const float* esw2  = (const float*)d_in[15];
    const float* esb2  = (const float*)d_in[16];
    const float* erw1  = (const float*)d_in[17];
    const float* erb1  = (const float*)d_in[18];
    const float* erw2  = (const float*)d_in[19];
    const float* erb2  = (const float*)d_in[20];
    const float* ln_gs = (const float*)d_in[21];
    const float* ln_bs = (const float*)d_in[22];
    const float* ln_gv = (const float*)d_in[23];

    const int N = in_sizes[0] / DDIM;
    const int E = in_sizes[3] / 2;

    // ---- workspace carving (64B aligned) ----
    char* p = (char*)d_ws;
    size_t o = 0;
    int* hist = (int*)(p + o);  o = align64(o + (size_t)N * 4);
    int* off  = (int*)(p + o);  o = align64(o + (size_t)(N + 1) * 4);
    int* cnt  = (int*)(p + o);  o = align64(o + (size_t)N * 4);
    int* perm = (int*)(p + o);  o = align64(o + (size_t)E * 4);
    bf16_t* ps_bf = (bf16_t*)(p + o); o = align64(o + (size_t)N * 128 * 2);
    bf16_t* pv_bf = (bf16_t*)(p + o); o = align64(o + (size_t)N * 192 * 2);
    bf16_t* xs_bf = (bf16_t*)(p + o); o = align64(o + (size_t)N * 128 * 2);
    bf16_t* xv_bf = (bf16_t*)(p + o); o = align64(o + (size_t)N * 192 * 2);
    bf16_t* esw1t = (bf16_t*)(p + o); o = align64(o + (size_t)128 * 320 * 2);
    bf16_t* esw2t = (bf16_t*)(p + o); o = align64(o + (size_t)384 * 128 * 2);
    bf16_t* erw1t = (bf16_t*)(p + o); o = align64(o + (size_t)128 * 32 * 2);
    bf16_t* erw2t = (bf16_t*)(p + o); o = align64(o + (size_t)384 * 128 * 2);
    bf16_t* w_bf  = (bf16_t*)(p + o); o = align64(o + (size_t)E * WNUM * 2);

    hipMemsetAsync(hist, 0, (size_t)N * 4, stream);
    k_wconv<<<64, 256, 0, stream>>>(esw1, esw2, erw1, erw2, esw1t, esw2t, erw1t, erw2t);
    k_nodeprep<<<(N + 15)/16, 256, 0, stream>>>(nf, w0s, b0s, w0v, w1s, b1s, w1v,
                                                ps_bf, pv_bf, xs_bf, xv_bf, N);
    k_hist<<<256, 256, 0, stream>>>(eidx, hist, E);
    k_scan<<<1, 1024, 0, stream>>>(hist, off, cnt, N);
    k_scatter<<<256, 256, 0, stream>>>(eidx, cnt, perm, E);
    k_edge2<<<(E + 63)/64, 512, 0, stream>>>(eidx, ea_g, ps_bf, pv_bf,
                                             esw1t, esw2t, erw1t, erw2t,
                                             esb1, esb2, erb1, erb2, w_bf, E);
    k_gather<<<N, 256, 0, stream>>>(perm, off, eidx, rshs, xs_bf, xv_bf, w_bf,
                                    nf, w2s, b2s, w2v, ln_gs, ln_bs, ln_gv,
                                    (float*)d_out, N, E);
}

// Round 3
// 376.748 us; speedup vs baseline: 2.6599x; 1.4158x over previous
//
#include <hip/hip_runtime.h>
#include <hip/hip_bf16.h>

typedef __bf16 bf16_t;
typedef __bf16 v8bf __attribute__((ext_vector_type(8)));
typedef float  v4f  __attribute__((ext_vector_type(4)));

#define NSC   128   // scalar channels
#define NVC   64    // vector channels
#define DDIM  320   // NSC + 3*NVC
#define HIDN  128
#define K1DIM 320   // 2*NSC + NVC
#define WNUM  384
#define S0STR 330   // padded LDS stride for s0 tile (bank ≡5 mod 32)
#define HSTR  138   // padded LDS stride for h1/h2

__device__ __forceinline__ float siluf(float x) { return x / (1.f + __expf(-x)); }

// ---------------- weight conversion into MFMA-fragment-packed bf16 ----------------
// Fragment layout for mfma_16x16x32_bf16 B-operand: lane l = (kg<<4)|lr holds
// row n = (frag's n-base) + lr, k = (frag's k-base) + kg*8 .. +8.
// Packed so one wave's load of a fragment is 64 lanes x 16B contiguous (1KB).
__global__ void k_wconv(const float* __restrict__ esw1, const float* __restrict__ esw2,
                        const float* __restrict__ erw1, const float* __restrict__ erw2,
                        bf16_t* __restrict__ p1, bf16_t* __restrict__ p2,
                        bf16_t* __restrict__ p3, bf16_t* __restrict__ p4)
{
    const int gid = blockIdx.x * blockDim.x + threadIdx.x;
    const int stride = gridDim.x * blockDim.x;
    // p1: es_w1 [320x128], frag = kk*8 + nj*4 + t  (kk 0..9)
    for (int i = gid; i < 80*512; i += stride) {
        int frag = i >> 9, w = i & 511, lane = w >> 3, j = w & 7;
        int kk = frag >> 3, nj = (frag >> 2) & 1, t = frag & 3;
        int lr = lane & 15, kg = lane >> 4;
        int n = nj*64 + t*16 + lr, k = kk*32 + kg*8 + j;
        p1[i] = (bf16_t)esw1[k*128 + n];
    }
    // p3: er_w1 [20x128] padded K->32, frag = nj*4 + t
    for (int i = gid; i < 8*512; i += stride) {
        int frag = i >> 9, w = i & 511, lane = w >> 3, j = w & 7;
        int nj = frag >> 2, t = frag & 3;
        int lr = lane & 15, kg = lane >> 4;
        int n = nj*64 + t*16 + lr, k = kg*8 + j;
        p3[i] = (k < 20) ? (bf16_t)erw1[k*128 + n] : (bf16_t)(0.f);
    }
    // p2/p4: es_w2 / er_w2 [128x384], frag = ch*32 + kk*8 + nj*4 + t
    for (int i = gid; i < 96*512; i += stride) {
        int frag = i >> 9, w = i & 511, lane = w >> 3, j = w & 7;
        int ch = frag >> 5, kk = (frag >> 3) & 3, nj = (frag >> 2) & 1, t = frag & 3;
        int lr = lane & 15, kg = lane >> 4;
        int n = ch*128 + nj*64 + t*16 + lr, k = kk*32 + kg*8 + j;
        p2[i] = (bf16_t)esw2[k*384 + n];
        p4[i] = (bf16_t)erw2[k*384 + n];
    }
}

// ---------------- counting sort by recv ----------------
__global__ void k_hist(const int* __restrict__ eidx, int* __restrict__ hist, int E)
{
    for (int e = blockIdx.x * blockDim.x + threadIdx.x; e < E; e += gridDim.x * blockDim.x)
        atomicAdd(&hist[eidx[e]], 1);
}

__global__ __launch_bounds__(1024) void k_scan(const int* __restrict__ hist,
                                               int* __restrict__ off, int* __restrict__ cnt, int N)
{
    __shared__ int part[1024];
    const int tid = threadIdx.x;
    const int C = (N + 1023) >> 10;
    const int base = tid * C;
    int s = 0;
    for (int j = 0; j < C; ++j) { int idx = base + j; if (idx < N) s += hist[idx]; }
    part[tid] = s;
    __syncthreads();
    for (int d = 1; d < 1024; d <<= 1) {
        int u = (tid >= d) ? part[tid - d] : 0;
        __syncthreads();
        part[tid] += u;
        __syncthreads();
    }
    int run = part[tid] - s;
    for (int j = 0; j < C; ++j) {
        int idx = base + j;
        if (idx < N) { off[idx] = run; cnt[idx] = run; run += hist[idx]; }
    }
    if (tid == 1023) off[N] = part[1023];
}

__global__ void k_scatter(const int* __restrict__ eidx, int* __restrict__ cnt,
                          int* __restrict__ perm, int E)
{
    for (int e = blockIdx.x * blockDim.x + threadIdx.x; e < E; e += gridDim.x * blockDim.x) {
        int pos = atomicAdd(&cnt[eidx[e]], 1);
        perm[pos] = e;
    }
}

// ---------------- node prep ----------------
__global__ __launch_bounds__(256) void k_nodeprep(
    const float* __restrict__ nf,
    const float* __restrict__ w0s, const float* __restrict__ b0s, const float* __restrict__ w0v,
    const float* __restrict__ w1s, const float* __restrict__ b1s, const float* __restrict__ w1v,
    bf16_t* __restrict__ ps_bf, bf16_t* __restrict__ pv_bf,
    bf16_t* __restrict__ xs_bf, bf16_t* __restrict__ xv_bf, int N)
{
    __shared__ float s_in[16][128];
    __shared__ float vt[3][64][16];   // [m][c][node]
    const int tid = threadIdx.x;
    const int nb = blockIdx.x * 16;
    const size_t N64 = (size_t)N * 64;

    for (int idx = tid; idx < 16*320; idx += 256) {
        int n = idx / 320, c = idx % 320;
        int gn = nb + n; if (gn >= N) gn = N - 1;
        float v = nf[(size_t)gn*320 + c];
        if (c < 128) s_in[n][c] = v;
        else { int q = c - 128; vt[q % 3][q / 3][n] = v; }
    }
    __syncthreads();

    {
        const int col = tid & 127, g = tid >> 7;
        float acc[8];
        #pragma unroll
        for (int j = 0; j < 8; ++j) acc[j] = 0.f;
        for (int c4 = 0; c4 < 128; c4 += 4) {
            float wa = w0s[(c4+0)*128 + col];
            float wb = w0s[(c4+1)*128 + col];
            float wc = w0s[(c4+2)*128 + col];
            float wd = w0s[(c4+3)*128 + col];
            #pragma unroll
            for (int j = 0; j < 8; ++j) {
                float4 sv = *(const float4*)&s_in[g*8+j][c4];
                acc[j] += sv.x*wa + sv.y*wb + sv.z*wc + sv.w*wd;
            }
        }
        float b = b0s[col];
        #pragma unroll
        for (int j = 0; j < 8; ++j) {
            int gn = nb + g*8 + j;
            if (gn < N) ps_bf[(size_t)gn*128 + col] = (bf16_t)(acc[j] + b);
        }
    }
    if (tid < 192) {
        const int d = tid & 63, m = tid >> 6;
        float acc[16];
        #pragma unroll
        for (int j = 0; j < 16; ++j) acc[j] = 0.f;
        for (int c = 0; c < 64; ++c) {
            float w = w0v[c*64 + d];
            float4 a0 = *(const float4*)&vt[m][c][0];
            float4 a1 = *(const float4*)&vt[m][c][4];
            float4 a2 = *(const float4*)&vt[m][c][8];
            float4 a3 = *(const float4*)&vt[m][c][12];
            acc[0]+=a0.x*w; acc[1]+=a0.y*w; acc[2]+=a0.z*w; acc[3]+=a0.w*w;
            acc[4]+=a1.x*w; acc[5]+=a1.y*w; acc[6]+=a1.z*w; acc[7]+=a1.w*w;
            acc[8]+=a2.x*w; acc[9]+=a2.y*w; acc[10]+=a2.z*w; acc[11]+=a2.w*w;
            acc[12]+=a3.x*w; acc[13]+=a3.y*w; acc[14]+=a3.z*w; acc[15]+=a3.w*w;
        }
        #pragma unroll
        for (int j = 0; j < 16; ++j) {
            int gn = nb + j;
            if (gn < N) pv_bf[(size_t)m*N64 + (size_t)gn*64 + d] = (bf16_t)acc[j];
        }
    }
    __syncthreads();

    for (int idx = tid; idx < 2048; idx += 256) {
        int n = idx >> 7, c = idx & 127;
        s_in[n][c] = siluf(s_in[n][c]);
    }
    for (int idx = tid; idx < 1024; idx += 256) {
        int n = idx & 15, cc = idx >> 4;
        float v0 = vt[0][cc][n], v1 = vt[1][cc][n], v2 = vt[2][cc][n];
        float nn = sqrtf(v0*v0 + v1*v1 + v2*v2 + 1e-10f);
        float sc = 1.f / (1.f + __expf(-nn));
        vt[0][cc][n] = v0*sc; vt[1][cc][n] = v1*sc; vt[2][cc][n] = v2*sc;
    }
    __syncthreads();

    {
        const int col = tid & 127, g = tid >> 7;
        float acc[8];
        #pragma unroll
        for (int j = 0; j < 8; ++j) acc[j] = 0.f;
        for (int c4 = 0; c4 < 128; c4 += 4) {
            float wa = w1s[(c4+0)*128 + col];
            float wb = w1s[(c4+1)*128 + col];
            float wc = w1s[(c4+2)*128 + col];
            float wd = w1s[(c4+3)*128 + col];
            #pragma unroll
            for (int j = 0; j < 8; ++j) {
                float4 sv = *(const float4*)&s_in[g*8+j][c4];
                acc[j] += sv.x*wa + sv.y*wb + sv.z*wc + sv.w*wd;
            }
        }
        float b = b1s[col];
        #pragma unroll
        for (int j = 0; j < 8; ++j) {
            int gn = nb + g*8 + j;
            if (gn < N) xs_bf[(size_t)gn*128 + col] = (bf16_t)(acc[j] + b);
        }
    }
    if (tid < 192) {
        const int d = tid & 63, m = tid >> 6;
        float acc[16];
        #pragma unroll
        for (int j = 0; j < 16; ++j) acc[j] = 0.f;
        for (int c = 0; c < 64; ++c) {
            float w = w1v[c*64 + d];
            float4 a0 = *(const float4*)&vt[m][c][0];
            float4 a1 = *(const float4*)&vt[m][c][4];
            float4 a2 = *(const float4*)&vt[m][c][8];
            float4 a3 = *(const float4*)&vt[m][c][12];
            acc[0]+=a0.x*w; acc[1]+=a0.y*w; acc[2]+=a0.z*w; acc[3]+=a0.w*w;
            acc[4]+=a1.x*w; acc[5]+=a1.y*w; acc[6]+=a1.z*w; acc[7]+=a1.w*w;
            acc[8]+=a2.x*w; acc[9]+=a2.y*w; acc[10]+=a2.z*w; acc[11]+=a2.w*w;
            acc[12]+=a3.x*w; acc[13]+=a3.y*w; acc[14]+=a3.z*w; acc[15]+=a3.w*w;
        }
        #pragma unroll
        for (int j = 0; j < 16; ++j) {
            int gn = nb + j;
            if (gn < N) xv_bf[(size_t)m*N64 + (size_t)gn*64 + d] = (bf16_t)acc[j];
        }
    }
}

// ---------------- edge MLP (MFMA bf16, packed weights) -> w[E][384] bf16 ----------------
__global__ __launch_bounds__(512) void k_edge2(
    const int* __restrict__ eidx, const float* __restrict__ ea_g,
    const bf16_t* __restrict__ ps_bf, const bf16_t* __restrict__ pv_bf,
    const bf16_t* __restrict__ p1, const bf16_t* __restrict__ p2,
    const bf16_t* __restrict__ p3, const bf16_t* __restrict__ p4,
    const float* __restrict__ es_b1, const float* __restrict__ es_b2,
    const float* __restrict__ er_b1, const float* __restrict__ er_b2,
    bf16_t* __restrict__ w_bf, int N, int E)
{
    __shared__ bf16_t s0h[64*S0STR];          // s0 tile; reused for h1/h2 (stride HSTR)
    __shared__ bf16_t eat[64*40];             // edge_attr tile, K padded to 32
    __shared__ int   recv_l[64], send_l[64];

    const int tid  = threadIdx.x;
    const int lane = tid & 63;
    const int wid  = tid >> 6;
    const int e0   = blockIdx.x * 64;
    const size_t N64 = (size_t)N * 64;

    if (tid < 64) {
        int e = e0 + tid; if (e >= E) e = E - 1;
        recv_l[tid] = eidx[e];
        send_l[tid] = eidx[E + e];
    }
    __syncthreads();

    #pragma unroll
    for (int rr = 0; rr < 8; ++rr) {
        int r = wid*8 + rr;
        int nr = recv_l[r], nsd = send_l[r];
        if (lane < 32) {
            *(uint2*)&s0h[r*S0STR + lane*4] = *(const uint2*)(ps_bf + (size_t)nr*NSC + lane*4);
        } else {
            int l2 = lane - 32;
            *(uint2*)&s0h[r*S0STR + 128 + l2*4] = *(const uint2*)(ps_bf + (size_t)nsd*NSC + l2*4);
        }
        // vdot: lane = vector channel c (plane layout -> coalesced 128B loads)
        float d = 0.f;
        #pragma unroll
        for (int m = 0; m < 3; ++m)
            d += (float)pv_bf[m*N64 + (size_t)nr*64 + lane] * (float)pv_bf[m*N64 + (size_t)nsd*64 + lane];
        s0h[r*S0STR + 256 + lane] = (bf16_t)d;
        if (lane < 32) {
            int e = e0 + r;
            float v = (lane < 20 && e < E) ? ea_g[(size_t)e*20 + lane] : 0.f;
            eat[r*40 + lane] = (bf16_t)v;
        }
    }
    __syncthreads();

    const int mi = wid >> 1;
    const int nj = wid & 1;
    const int lr = lane & 15;
    const int kg = lane >> 4;

    v4f acc1[4], acc3[4];
    #pragma unroll
    for (int t = 0; t < 4; ++t) { acc1[t] = (v4f){0.f,0.f,0.f,0.f}; acc3[t] = (v4f){0.f,0.f,0.f,0.f}; }

    const bf16_t* aBase = &s0h[(mi*16 + lr)*S0STR + kg*8];
    #pragma unroll
    for (int kk = 0; kk < 10; ++kk) {
        v8bf a = *(const v8bf*)(aBase + kk*32);
        #pragma unroll
        for (int t = 0; t < 4; ++t) {
            v8bf b = *(const v8bf*)(p1 + ((kk*2 + nj)*4 + t)*512 + lane*8);
            acc1[t] = __builtin_amdgcn_mfma_f32_16x16x32_bf16(a, b, acc1[t], 0, 0, 0);
        }
    }
    {
        v8bf a = *(const v8bf*)&eat[(mi*16 + lr)*40 + kg*8];
        #pragma unroll
        for (int t = 0; t < 4; ++t) {
            v8bf b = *(const v8bf*)(p3 + (nj*4 + t)*512 + lane*8);
            acc3[t] = __builtin_amdgcn_mfma_f32_16x16x32_bf16(a, b, acc3[t], 0, 0, 0);
        }
    }
    __syncthreads();   // all reads of s0h/eat done; reuse s0h for h1/h2

    bf16_t* h1 = s0h;              // 64 x HSTR
    bf16_t* h2 = s0h + 64*HSTR;
    #pragma unroll
    for (int t = 0; t < 4; ++t) {
        int col = nj*64 + t*16 + lr;
        float be = es_b1[col];
        float br = er_b1[col];
        #pragma unroll
        for (int r = 0; r < 4; ++r) {
            int row = mi*16 + kg*4 + r;
            h1[row*HSTR + col] = (bf16_t)siluf(acc1[t][r] + be);
            h2[row*HSTR + col] = (bf16_t)siluf(acc3[t][r] + br);
        }
    }
    __syncthreads();

    #pragma unroll
    for (int ch = 0; ch < 3; ++ch) {
        v4f aes[4], aer[4];
        #pragma unroll
        for (int t = 0; t < 4; ++t) { aes[t] = (v4f){0.f,0.f,0.f,0.f}; aer[t] = (v4f){0.f,0.f,0.f,0.f}; }
        #pragma unroll
        for (int kk = 0; kk < 4; ++kk) {
            v8bf a1 = *(const v8bf*)&h1[(mi*16 + lr)*HSTR + kk*32 + kg*8];
            v8bf a2 = *(const v8bf*)&h2[(mi*16 + lr)*HSTR + kk*32 + kg*8];
            #pragma unroll
            for (int t = 0; t < 4; ++t) {
                int off = (((ch*4 + kk)*2 + nj)*4 + t)*512 + lane*8;
                v8bf b1 = *(const v8bf*)(p2 + off);
                v8bf b2 = *(const v8bf*)(p4 + off);
                aes[t] = __builtin_amdgcn_mfma_f32_16x16x32_bf16(a1, b1, aes[t], 0, 0, 0);
                aer[t] = __builtin_amdgcn_mfma_f32_16x16x32_bf16(a2, b2, aer[t], 0, 0, 0);
            }
        }
        #pragma unroll
        for (int t = 0; t < 4; ++t) {
            int col = ch*128 + nj*64 + t*16 + lr;
            float be = es_b2[col], br = er_b2[col];
            #pragma unroll
            for (int r = 0; r < 4; ++r) {
                int row = mi*16 + kg*4 + r;
                int e = e0 + row;
                if (e < E) w_bf[(size_t)e*WNUM + col] = (bf16_t)((aes[t][r] + be) * (aer[t][r] + br));
            }
        }
    }
}

// ---------------- per-node gather + lin2 + norms + residual (no atomics) ----------------
__global__ __launch_bounds__(256) void k_gather(
    const int* __restrict__ perm, const int* __restrict__ off,
    const int* __restrict__ eidx, const float* __restrict__ rshs,
    const bf16_t* __restrict__ xs_bf, const bf16_t* __restrict__ xv_bf,
    const bf16_t* __restrict__ w_bf,
    const float* __restrict__ nf,
    const float* __restrict__ w2s, const float* __restrict__ b2s, const float* __restrict__ w2v,
    const float* __restrict__ ln_gs, const float* __restrict__ ln_bs, const float* __restrict__ ln_gv,
    float* __restrict__ out, int N, int E)
{
    __shared__ float accS_l[192];
    __shared__ float accV_l[576];
    __shared__ float os_l[128];
    __shared__ float ov_l[192];
    __shared__ float stats[3];
    const int tid = threadIdx.x;
    const int n = blockIdx.x;
    const int i0 = off[n], i1 = off[n+1];
    const size_t N64 = (size_t)N * 64;

    float a0 = 0.f, a1 = 0.f, a2 = 0.f, a3 = 0.f;
    if (tid < 128) {
        const int c = tid;
        for (int i = i0; i < i1; ++i) {
            int e = perm[i];
            int nsd = eidx[E + e];
            float4 y = *(const float4*)(rshs + (size_t)e*4);
            float w1 = (float)w_bf[(size_t)e*WNUM + c];
            float w2 = (float)w_bf[(size_t)e*WNUM + 128 + c];
            float xs = (float)xs_bf[(size_t)nsd*NSC + c];
            a0 += xs * y.x * w1;
            float xw = xs * w2;
            a1 += xw * y.y; a2 += xw * y.z; a3 += xw * y.w;
        }
        accS_l[c] = a0;
        accV_l[c*3+0] = a1; accV_l[c*3+1] = a2; accV_l[c*3+2] = a3;
    } else if (tid < 192) {
        const int u = tid - 128;
        for (int i = i0; i < i1; ++i) {
            int e = perm[i];
            int nsd = eidx[E + e];
            float4 y = *(const float4*)(rshs + (size_t)e*4);
            float w3 = (float)w_bf[(size_t)e*WNUM + 256 + u];
            float w4 = (float)w_bf[(size_t)e*WNUM + 320 + u];
            float v0 = (float)xv_bf[0*N64 + (size_t)nsd*64 + u];
            float v1 = (float)xv_bf[1*N64 + (size_t)nsd*64 + u];
            float v2 = (float)xv_bf[2*N64 + (size_t)nsd*64 + u];
            a0 += (v0*y.y + v1*y.z + v2*y.w) * w4 * 0.57735026918962576f;
            float s = y.x * w3;
            a1 += v0*s; a2 += v1*s; a3 += v2*s;
        }
        accS_l[128+u] = a0;
        accV_l[(128+u)*3+0] = a1; accV_l[(128+u)*3+1] = a2; accV_l[(128+u)*3+2] = a3;
    }
    __syncthreads();

    if (tid < 128) {
        float acc = 0.f;
        #pragma unroll 4
        for (int c = 0; c < 192; ++c) acc += accS_l[c] * w2s[c*128 + tid];
        os_l[tid] = acc + b2s[tid];
    } else {
        int q = tid - 128;
        for (int o = q; o < 192; o += 128) {
            int m = o % 3, d = o / 3;
            float acc = 0.f;
            #pragma unroll 4
            for (int c = 0; c < 192; ++c) acc += accV_l[c*3 + m] * w2v[c*64 + d];
            ov_l[o] = acc;
        }
    }
    __syncthreads();

    if (tid < 64) {
        float x0 = os_l[tid], x1 = os_l[tid + 64];
        float s = x0 + x1;
        #pragma unroll
        for (int o = 32; o > 0; o >>= 1) s += __shfl_xor(s, o);
        float mu = s * (1.f/128.f);
        float d0 = x0 - mu, d1 = x1 - mu;
        float q = d0*d0 + d1*d1;
        #pragma unroll
        for (int o = 32; o > 0; o >>= 1) q += __shfl_xor(q, o);
        float var = q * (1.f/128.f);
        float v0 = ov_l[tid], v1 = ov_l[tid + 64], v2 = ov_l[tid + 128];
        float q2 = v0*v0 + v1*v1 + v2*v2;
        #pragma unroll
        for (int o = 32; o > 0; o >>= 1) q2 += __shfl_xor(q2, o);
        float n2 = q2 * (1.f/64.f);
        if (tid == 0) {
            stats[0] = mu;
            stats[1] = rsqrtf(var + 1e-5f);
            stats[2] = rsqrtf(n2 + 1e-5f);
        }
    }
    __syncthreads();

    const float mu = stats[0], rstd = stats[1], rn2 = stats[2];
    const size_t base = (size_t)n * DDIM;
    for (int i = tid; i < DDIM; i += 256) {
        if (i < 128) {
            out[base + i] = nf[base + i] + (os_l[i] - mu) * rstd * ln_gs[i] + ln_bs[i];
        } else {
            int o = i - 128;
            int d = o / 3;
            out[base + i] = nf[base + i] + ov_l[o] * rn2 * ln_gv[128 + d];
        }
    }
}

static inline size_t align64(size_t x) { return (x + 63) & ~(size_t)63; }

extern "C" void kernel_launch(void* const* d_in, const int* in_sizes, int n_in,
                              void* d_out, int out_size, void* d_ws, size_t ws_size,
                              hipStream_t stream)
{
    const float* nf    = (const float*)d_in[0];
    const float* ea_g  = (const float*)d_in[1];
    const float* rshs  = (const float*)d_in[2];
    const int*   eidx  = (const int*)  d_in[3];
    const float* w0s   = (const float*)d_in[4];
    const float* b0s   = (const float*)d_in[5];
    const float* w0v   = (const float*)d_in[6];
    const float* w1s   = (const float*)d_in[7];
    const float* b1s   = (const float*)d_in[8];
    const float* w1v   = (const float*)d_in[9];
    const float* w2s   = (const float*)d_in[10];
    const float* b2s   = (const float*)d_in[11];
    const float* w2v   = (const float*)d_in[12];
    const float* esw1  = (const float*)d_in[13];
    const float* esb1  = (const float*)d_in[14];
    const float* esw2  = (const float*)d_in[15];
    const float* esb2  = (const float*)d_in[16];
    const float* erw1  = (const float*)d_in[17];
    const float* erb1  = (const float*)d_in[18];
    const float* erw2  = (const float*)d_in[19];
    const float* erb2  = (const float*)d_in[20];
    const float* ln_gs = (const float*)d_in[21];
    const float* ln_bs = (const float*)d_in[22];
    const float* ln_gv = (const float*)d_in[23];

    const int N = in_sizes[0] / DDIM;
    const int E = in_sizes[3] / 2;

    char* p = (char*)d_ws;
    size_t o = 0;
    int* hist = (int*)(p + o);  o = align64(o + (size_t)N * 4);
    int* off  = (int*)(p + o);  o = align64(o + (size_t)(N + 1) * 4);
    int* cnt  = (int*)(p + o);  o = align64(o + (size_t)N * 4);
    int* perm = (int*)(p + o);  o = align64(o + (size_t)E * 4);
    bf16_t* ps_bf = (bf16_t*)(p + o); o = align64(o + (size_t)N * 128 * 2);
    bf16_t* pv_bf = (bf16_t*)(p + o); o = align64(o + (size_t)N * 192 * 2);
    bf16_t* xs_bf = (bf16_t*)(p + o); o = align64(o + (size_t)N * 128 * 2);
    bf16_t* xv_bf = (bf16_t*)(p + o); o = align64(o + (size_t)N * 192 * 2);
    bf16_t* p1 = (bf16_t*)(p + o); o = align64(o + (size_t)80 * 512 * 2);
    bf16_t* p2 = (bf16_t*)(p + o); o = align64(o + (size_t)96 * 512 * 2);
    bf16_t* p3 = (bf16_t*)(p + o); o = align64(o + (size_t)8  * 512 * 2);
    bf16_t* p4 = (bf16_t*)(p + o); o = align64(o + (size_t)96 * 512 * 2);
    bf16_t* w_bf  = (bf16_t*)(p + o); o = align64(o + (size_t)E * WNUM * 2);

    hipMemsetAsync(hist, 0, (size_t)N * 4, stream);
    k_wconv<<<64, 256, 0, stream>>>(esw1, esw2, erw1, erw2, p1, p2, p3, p4);
    k_nodeprep<<<(N + 15)/16, 256, 0, stream>>>(nf, w0s, b0s, w0v, w1s, b1s, w1v,
                                                ps_bf, pv_bf, xs_bf, xv_bf, N);
    k_hist<<<256, 256, 0, stream>>>(eidx, hist, E);
    k_scan<<<1, 1024, 0, stream>>>(hist, off, cnt, N);
    k_scatter<<<256, 256, 0, stream>>>(eidx, cnt, perm, E);
    k_edge2<<<(E + 63)/64, 512, 0, stream>>>(eidx, ea_g, ps_bf, pv_bf,
                                             p1, p2, p3, p4,
                                             esb1, esb2, erb1, erb2, w_bf, N, E);
    k_gather<<<N, 256, 0, stream>>>(perm, off, eidx, rshs, xs_bf, xv_bf, w_bf,
                                    nf, w2s, b2s, w2v, ln_gs, ln_bs, ln_gv,
                                    (float*)d_out, N, E);
}